// Round 4
// baseline (525.309 us; speedup 1.0000x reference)
//
#include <hip/hip_runtime.h>
#include <math.h>

// Problem constants
#define EXPERTS 8
#define DDIM 2048
#define HDIM 2048
#define NTOK 4096
#define NPAIR 8192
#define MAXSLOT 10240   // 8192 + 8*127 rounded up (128-padded per expert)
#define MAXTILE 72      // max sum of ceil(cnt_e/128) = 64 + 8

typedef _Float16 f16;
typedef __attribute__((ext_vector_type(8))) _Float16 f16x8;
typedef __attribute__((ext_vector_type(2))) _Float16 f16x2;
typedef __attribute__((ext_vector_type(4))) float f32x4;

// ---- workspace layout (bytes); peak ~193 MB ----
// Phase 1: gup_t f16 [E][4096][2048] at 0..128MB (transposed gate_up)
// Phase 2 (after GEMM1, gup_t dead): y f16 [MAXSLOT][2048] at 0..41.9MB,
//          down_t f16 [E][2048][2048] at 41.9..109MB
#define GUPT_OFF 0ull
#define Y_OFF    0ull
#define DWNT_OFF 41943040ull
#define XF_OFF   134217728ull    // f16 [NTOK][2048] = 16MB
#define ACT_OFF  150994944ull    // f16 [MAXSLOT][2048] = 41.9MB
#define CTRL_OFF 192937984ull
// ctrl (ints): slot_tok[10240]@0, tok_slot[8192]@10240, cnt[8]@18432,
// cursor[8]@18440, tile_e[72]@18448, tile_r0[72]@18520, n_tiles@18592,
// is32@18593, slot_w(float)[10240]@18600
#define CTRL_INTS 28840

#define BARRIER() asm volatile("s_barrier" ::: "memory")
#define VMCNT4()  asm volatile("s_waitcnt vmcnt(4)" ::: "memory")
#define VMCNT0()  asm volatile("s_waitcnt vmcnt(0)" ::: "memory")

__device__ __forceinline__ void gload_lds16(const void* g, void* l) {
  __builtin_amdgcn_global_load_lds(
      (const __attribute__((address_space(1))) unsigned int*)g,
      (__attribute__((address_space(3))) unsigned int*)l,
      16, 0, 0);
}

// ---------------- routing ----------------
__global__ void k_detect(const int* __restrict__ w, int* flag) {
  int i = blockIdx.x * blockDim.x + threadIdx.x;
  if (i < NPAIR / 2 && w[2 * i + 1] != 0) atomicOr(flag, 1);
}

__device__ __forceinline__ int expert_of(const int* idx, int is32, int p) {
  return is32 ? idx[p] : idx[2 * p];
}

__global__ void k_count(const int* __restrict__ idx, const int* __restrict__ flag,
                        int* cnt) {
  int p = blockIdx.x * blockDim.x + threadIdx.x;
  if (p < NPAIR) atomicAdd(&cnt[expert_of(idx, *flag, p)], 1);
}

__global__ void k_plan(const int* __restrict__ cnt, int* cursor,
                       int* tile_e, int* tile_r0, int* n_tiles) {
  if (blockIdx.x == 0 && threadIdx.x == 0) {
    int off = 0, nt = 0;
    for (int e = 0; e < EXPERTS; ++e) {
      cursor[e] = off;
      int t = (cnt[e] + 127) >> 7;
      for (int i = 0; i < t; ++i) { tile_e[nt] = e; tile_r0[nt] = off + i * 128; ++nt; }
      off += t * 128;
    }
    *n_tiles = nt;
  }
}

__global__ void k_assign(const int* __restrict__ idx, const int* __restrict__ flag,
                         const float* __restrict__ wts, const float* __restrict__ scale,
                         int* cursor, int* slot_tok, int* tok_slot, float* slot_w) {
  int p = blockIdx.x * blockDim.x + threadIdx.x;
  if (p < NPAIR) {
    int e = expert_of(idx, *flag, p);
    int pos = atomicAdd(&cursor[e], 1);
    slot_tok[pos] = p >> 1;
    tok_slot[p] = pos;
    slot_w[pos] = wts[p] * scale[e];
  }
}

__global__ void k_cvt_x(const float* __restrict__ in, f16* __restrict__ out) {
  int i = blockIdx.x * blockDim.x + threadIdx.x;
  float4 v = ((const float4*)in)[i];
  typedef __attribute__((ext_vector_type(4))) _Float16 f16x4;
  f16x4 o = {(f16)v.x, (f16)v.y, (f16)v.z, (f16)v.w};
  ((f16x4*)out)[i] = o;
}

// fp32 [R][C] -> f16 [C][R], per expert (blockIdx.z); f16x2 stores
__global__ void k_transpose(const float* __restrict__ in, f16* __restrict__ out,
                            int R, int C) {
  __shared__ float t[32][33];
  const size_t base = (size_t)blockIdx.z * R * C;
  const float* ip = in + base;
  f16* op = out + base;
  int c0 = blockIdx.x * 32, r0 = blockIdx.y * 32;
  int tx = threadIdx.x, ty = threadIdx.y;
#pragma unroll
  for (int i = 0; i < 32; i += 8)
    t[ty + i][tx] = ip[(size_t)(r0 + ty + i) * C + c0 + tx];
  __syncthreads();
  // out[(c0+j)*R + r0+k] = t[k][j]; thread: k-pair p=tx&15, row-half h=tx>>4
  const int p = tx & 15, h = tx >> 4;
#pragma unroll
  for (int i = 0; i < 2; ++i) {
    const int j = ty + h * 8 + i * 16;
    f16x2 v = {(f16)t[2 * p][j], (f16)t[2 * p + 1][j]};
    *(f16x2*)&op[(size_t)(c0 + j) * R + r0 + 2 * p] = v;
  }
}

// ---------------- 128x128x32 tri-buffered grouped GEMM ----------------
// 4 waves (2M x 2N), wave-out 64x64, acc[4][4] (64 VGPR), LDS 48KB -> 3 blk/CU.
// 1 barrier + counted vmcnt(4) per K-tile; 2-deep prefetch via 3 buffers.
// G1: A = gathered x rows; B = gup_t strip (rows 0-63 gate, 64-127 up);
//     epilogue: LDS exchange + exact gelu -> act.
// G0: A = act rows (direct); B = down_t strip; epilogue -> y.
template <int G1>
__global__ __launch_bounds__(256, 3) void k_gemm(
    const f16* __restrict__ Asrc, const f16* __restrict__ Bsrc,
    const int* __restrict__ slot_tok,
    const int* __restrict__ tile_e, const int* __restrict__ tile_r0,
    const int* __restrict__ n_tiles, f16* __restrict__ dst) {
  __shared__ __align__(16) f16 smem[3][8192];  // per buf: A 4096, B 4096 f16

  // bijective XCD swizzle; bx-fastest so same-nt blocks share an XCD's L2
  const int nbx = MAXTILE, nby = G1 ? 32 : 16;
  const int nwg = nbx * nby, q = nwg / 8;
  int oid = (int)(blockIdx.y * nbx + blockIdx.x);
  int nid = (oid % 8) * q + oid / 8;
  const int bx = nid % nbx, nt = nid / nbx;
  if (bx >= *n_tiles) return;
  const int e = tile_e[bx];
  const int m0 = tile_r0[bx];

  const int tid = threadIdx.x;
  const int lane = tid & 63;
  const int wv = tid >> 6;
  const int wrM = wv >> 1;   // 0..1 : 64-row half
  const int wcl = wv & 1;    // 0..1 : 64-col half
  const int fr = lane & 15;
  const int fhi = lane >> 4;

  // staging: instr i covers rows [i*64, i*64+64); thread row rlb, chunk tid&3,
  // source chunk inverse-swizzled (LDS dest linear; reads re-swizzle).
  const int rlb = tid >> 2;                     // 0..63
  const int csw = (tid & 3) ^ ((rlb >> 1) & 3); // 2-way-free swizzle for BK=32
  const f16* aS[2];
  const f16* bS[2];
#pragma unroll
  for (int i = 0; i < 2; ++i) {
    size_t arow = G1 ? (size_t)slot_tok[m0 + i * 64 + rlb] : (size_t)(m0 + i * 64 + rlb);
    aS[i] = Asrc + arow * 2048 + csw * 8;
    size_t brow;
    if (G1) brow = (size_t)e * 4096 + (i ? (size_t)2048 : 0) + (size_t)nt * 64 + rlb;
    else    brow = (size_t)e * 2048 + (size_t)nt * 128 + i * 64 + rlb;
    bS[i] = Bsrc + brow * 2048 + csw * 8;
  }

  auto stage = [&](int s, int kt) {
    const size_t ko = (size_t)kt * 32;
#pragma unroll
    for (int i = 0; i < 2; ++i)
      gload_lds16(aS[i] + ko, &smem[s][i * 2048 + tid * 8]);
#pragma unroll
    for (int i = 0; i < 2; ++i)
      gload_lds16(bS[i] + ko, &smem[s][4096 + i * 2048 + tid * 8]);
  };

  f32x4 acc[4][4];
#pragma unroll
  for (int i = 0; i < 4; ++i)
#pragma unroll
    for (int j = 0; j < 4; ++j) acc[i][j] = (f32x4){0.f, 0.f, 0.f, 0.f};

  // prologue: stage kt=0,1; vmcnt(4) completes stage0 (stage1's 4 in flight)
  stage(0, 0);
  stage(1, 1);
  VMCNT4();
  BARRIER();

  const int NT = DDIM / 32;  // 64
  int s = 0;
  for (int kt = 0; kt < NT; ++kt) {
    int sn = s + 2; if (sn >= 3) sn -= 3;
    if (kt + 2 < NT) stage(sn, kt + 2);

    const f16* As = &smem[s][0];
    const f16* Bs = &smem[s][4096];
    f16x8 bfr[4];
#pragma unroll
    for (int ci = 0; ci < 4; ++ci) {
      const int r = wcl * 64 + ci * 16 + fr;
      bfr[ci] = *(const f16x8*)&Bs[r * 32 + ((fhi ^ ((r >> 1) & 3)) << 3)];
    }
#pragma unroll
    for (int t = 0; t < 4; ++t) {
      const int r = wrM * 64 + t * 16 + fr;
      const f16x8 af = *(const f16x8*)&As[r * 32 + ((fhi ^ ((r >> 1) & 3)) << 3)];
#pragma unroll
      for (int ci = 0; ci < 4; ++ci)
        acc[t][ci] = __builtin_amdgcn_mfma_f32_16x16x32_f16(af, bfr[ci],
                                                            acc[t][ci], 0, 0, 0);
    }
    // boundary: stage(kt+1) must be landed for next iter; keep stage(kt+2) in flight
    if (kt + 3 < NT) { VMCNT4(); } else { VMCNT0(); }
    BARRIER();
    s = (s == 2) ? 0 : s + 1;
  }

  if (G1) {
    // up waves (wcl==1) pass acc through LDS; gate waves apply exact gelu
    float* xb = (float*)&smem[0][0];  // [128][68] f32 = 34.8KB < 48KB
    if (wcl == 1) {
#pragma unroll
      for (int t = 0; t < 4; ++t)
#pragma unroll
        for (int ci = 0; ci < 4; ++ci)
#pragma unroll
          for (int rg = 0; rg < 4; ++rg)
            xb[(wrM * 64 + t * 16 + fhi * 4 + rg) * 68 + ci * 16 + fr] =
                acc[t][ci][rg];
    }
    BARRIER();
    if (wcl == 0) {
#pragma unroll
      for (int t = 0; t < 4; ++t)
#pragma unroll
        for (int ci = 0; ci < 4; ++ci)
#pragma unroll
          for (int rg = 0; rg < 4; ++rg) {
            const int row = wrM * 64 + t * 16 + fhi * 4 + rg;
            const int gc = ci * 16 + fr;
            const float u = xb[row * 68 + gc];
            const float g = acc[t][ci][rg];
            const float a = 0.5f * g * (1.0f + erff(g * 0.70710678118654752f)) * u;
            dst[(size_t)(m0 + row) * 2048 + (size_t)nt * 64 + gc] = (f16)a;
          }
    }
  } else {
#pragma unroll
    for (int t = 0; t < 4; ++t)
#pragma unroll
      for (int ci = 0; ci < 4; ++ci)
#pragma unroll
        for (int rg = 0; rg < 4; ++rg)
          dst[(size_t)(m0 + wrM * 64 + t * 16 + fhi * 4 + rg) * 2048 +
              (size_t)nt * 128 + wcl * 64 + ci * 16 + fr] = (f16)acc[t][ci][rg];
  }
}

// out[tok] = w(s0)*y[s0] + w(s1)*y[s1]  (fully writes out; no memset needed)
__global__ void k_combine(const f16* __restrict__ y, const float* __restrict__ slot_w,
                          const int* __restrict__ tok_slot, float* __restrict__ out) {
  const int gid = blockIdx.x * blockDim.x + threadIdx.x;
  const int tok = gid >> 8;
  const int c = (gid & 255) * 8;
  const int s0 = tok_slot[2 * tok], s1 = tok_slot[2 * tok + 1];
  const float w0 = slot_w[s0], w1 = slot_w[s1];
  const f16x8 v0 = *(const f16x8*)&y[(size_t)s0 * 2048 + c];
  const f16x8 v1 = *(const f16x8*)&y[(size_t)s1 * 2048 + c];
  float o[8];
#pragma unroll
  for (int j = 0; j < 8; ++j) o[j] = w0 * (float)v0[j] + w1 * (float)v1[j];
  float4* op = (float4*)&out[(size_t)tok * 2048 + c];
  op[0] = (float4){o[0], o[1], o[2], o[3]};
  op[1] = (float4){o[4], o[5], o[6], o[7]};
}

extern "C" void kernel_launch(void* const* d_in, const int* in_sizes, int n_in,
                              void* d_out, int out_size, void* d_ws, size_t ws_size,
                              hipStream_t stream) {
  const float* x = (const float*)d_in[0];
  const float* wts = (const float*)d_in[1];
  const int* idx = (const int*)d_in[2];
  const float* gup = (const float*)d_in[3];
  const float* dwn = (const float*)d_in[4];
  const float* scale = (const float*)d_in[5];
  float* out = (float*)d_out;

  char* ws = (char*)d_ws;
  f16* gup_t = (f16*)(ws + GUPT_OFF);
  f16* y = (f16*)(ws + Y_OFF);          // aliases gup_t (dead after GEMM1)
  f16* down_t = (f16*)(ws + DWNT_OFF);  // aliases gup_t tail (dead after GEMM1)
  f16* xf = (f16*)(ws + XF_OFF);
  f16* act = (f16*)(ws + ACT_OFF);
  int* ctrl = (int*)(ws + CTRL_OFF);
  int* slot_tok = ctrl;
  int* tok_slot = ctrl + 10240;
  int* cnt = ctrl + 18432;
  int* cursor = ctrl + 18440;
  int* tile_e = ctrl + 18448;
  int* tile_r0 = ctrl + 18520;
  int* n_tiles = ctrl + 18592;
  int* is32 = ctrl + 18593;
  float* slot_w = (float*)(ctrl + 18600);

  hipMemsetAsync(ctrl, 0, (size_t)CTRL_INTS * sizeof(int), stream);

  k_detect<<<NPAIR / 2 / 256, 256, 0, stream>>>(idx, is32);
  k_count<<<NPAIR / 256, 256, 0, stream>>>(idx, is32, cnt);
  k_plan<<<1, 1, 0, stream>>>(cnt, cursor, tile_e, tile_r0, n_tiles);
  k_assign<<<NPAIR / 256, 256, 0, stream>>>(idx, is32, wts, scale, cursor,
                                            slot_tok, tok_slot, slot_w);
  k_cvt_x<<<NTOK * DDIM / 4 / 256, 256, 0, stream>>>(x, xf);
  k_transpose<<<dim3(4096 / 32, 2048 / 32, EXPERTS), dim3(32, 8), 0, stream>>>(
      gup, gup_t, 2048, 4096);
  k_gemm<1><<<dim3(MAXTILE, 32), 256, 0, stream>>>(xf, gup_t, slot_tok, tile_e,
                                                   tile_r0, n_tiles, act);
  // gup_t dead now; transpose down into its tail, y into its head
  k_transpose<<<dim3(2048 / 32, 2048 / 32, EXPERTS), dim3(32, 8), 0, stream>>>(
      dwn, down_t, 2048, 2048);
  k_gemm<0><<<dim3(MAXTILE, 16), 256, 0, stream>>>(act, down_t, slot_tok, tile_e,
                                                   tile_r0, n_tiles, y);
  k_combine<<<NTOK, 256, 0, stream>>>(y, slot_w, tok_slot, out);
}